// Round 5
// baseline (78760.431 us; speedup 1.0000x reference)
//
#include <hip/hip_runtime.h>
#include <hip/hip_bf16.h>
#include <hip/hip_fp16.h>
#include <math.h>

#define CS 96      // source len
#define CT 96      // target len
#define CE 256     // embed
#define CH 512     // hidden
#define CH2 1024
#define CH3 1536
#define CV 32000
#define CXD 1280   // E + 2H

typedef unsigned int u32;
typedef unsigned short u16;
typedef unsigned long long u64;

__device__ __forceinline__ float sigm(float x){ return 1.f/(1.f+expf(-x)); }

// packed-fp16 dot2 with fp32 accumulate
__device__ __forceinline__ float dot2f(u32 a, u32 b, float c){
#if __has_builtin(__builtin_amdgcn_fdot2)
  typedef _Float16 hv2 __attribute__((ext_vector_type(2)));
  hv2 x = __builtin_bit_cast(hv2, a), y = __builtin_bit_cast(hv2, b);
  return __builtin_amdgcn_fdot2(x, y, c, false);
#else
  __half2 x = __builtin_bit_cast(__half2, a), y = __builtin_bit_cast(__half2, b);
  return c + __half2float(x.x)*__half2float(y.x) + __half2float(x.y)*__half2float(y.y);
#endif
}

__device__ __forceinline__ u32 packh2(float a, float b){
  return (u32)__half_as_ushort(__float2half(a)) | ((u32)__half_as_ushort(__float2half(b)) << 16);
}

// ---------------- init: exchange slots + cov_last ----------------
__global__ void k_init(u32* hx, float* cov_last){
  int i = threadIdx.x;
  for (int j = i; j < 8*CH; j += 256) hx[j] = 0u;   // hxF[2][CH] + hxS[2][CH] u64 -> 8*CH u32
  for (int j = i; j < CH; j += 256) cov_last[j] = 0.f;
}

// ---------------- embedding gathers ----------------
__global__ void k_embed(const int* iseq, const int* oseq, const float* ee, const float* de,
                        float* x_enc, float* x_dec){
  int s = blockIdx.x, d = threadIdx.x;
  x_enc[s*CE+d] = ee[(long)iseq[s]*CE + d];
  x_dec[s*CE+d] = de[(long)oseq[s]*CE + d];
}

// ---------------- encoder input-gate precompute ----------------
__global__ void k_gi(const float* Wf, const float* bf, const float* Wb, const float* bb,
                     const float* x_enc, float* gf, float* gb){
  int idx = blockIdx.x*256 + threadIdx.x;
  int dir = idx / (CS*CH3);
  int rem = idx - dir*(CS*CH3);
  int s = rem / CH3, r = rem - s*CH3;
  const float* W = dir ? Wb : Wf;
  const float* b = dir ? bb : bf;
  const float* x = x_enc + s*CE;
  const float* w = W + (long)r*CE;
  float acc = b[r];
  #pragma unroll 8
  for (int k=0;k<CE;k++) acc += w[k]*x[k];
  (dir ? gb : gf)[s*CH3 + r] = acc;
}

// ---------------- one encoder step ----------------
__global__ void k_enc_step(int s, const float* Whf, const float* bhf, const float* Whb, const float* bhb,
                           const float* gf, const float* gb, float* outf, float* outb){
  int wg = blockIdx.x;
  int dir = wg >> 3;
  int jb = (wg & 7)*64;
  int t = threadIdx.x;
  int j = jb + (t>>2);
  int c0 = (t&3)*128;
  const float* Whh = dir ? Whb : Whf;
  const float* bhh = dir ? bhb : bhf;
  const float* gi  = dir ? gb : gf;
  float* o = dir ? outb : outf;
  int pos = dir ? (CS-1-s) : s;
  const float* hp = (s>0) ? (o + (dir ? (pos+1)*CH : (s-1)*CH)) : nullptr;
  float ar=0.f, az=0.f, an=0.f;
  if (s > 0){
    const float* wr = Whh + (long)j*CH;
    const float* wz = Whh + (long)(j+CH)*CH;
    const float* wn = Whh + (long)(j+2*CH)*CH;
    #pragma unroll 4
    for (int k=c0;k<c0+128;k++){
      float h = hp[k];
      ar += wr[k]*h; az += wz[k]*h; an += wn[k]*h;
    }
  }
  ar += __shfl_xor(ar,1); ar += __shfl_xor(ar,2);
  az += __shfl_xor(az,1); az += __shfl_xor(az,2);
  an += __shfl_xor(an,1); an += __shfl_xor(an,2);
  if ((t&3)==0){
    const float* g = gi + pos*CH3;
    float hpj = (s>0) ? hp[j] : 0.f;
    float r = sigm(g[j]       + ar + bhh[j]);
    float z = sigm(g[j+CH]    + az + bhh[j+CH]);
    float n = tanhf(g[j+2*CH] + r*(an + bhh[j+2*CH]));
    o[pos*CH + j] = (1.f-z)*n + z*hpj;
  }
}

// ---------------- ua_enc / Aenc precompute + h_carry init ----------------
__global__ void k_prep2(const float* ua, const float* Wic, const float* outf, const float* outb,
                        float* ua_enc, float* Aenc, float* h_carry){
  int idx = blockIdx.x*256 + threadIdx.x;
  if (idx < 2*CS*CH){
    int which = idx / (CS*CH);
    int rem = idx - which*(CS*CH);
    int s = rem / CH, r = rem - s*CH;
    const float* of = outf + s*CH;
    const float* ob = outb + s*CH;
    const float* w = which ? (Wic + (long)r*CH3) : (ua + (long)r*CH2);
    float acc = 0.f;
    #pragma unroll 4
    for (int k=0;k<CH;k++) acc += w[k]*of[k];
    #pragma unroll 4
    for (int k=0;k<CH;k++) acc += w[CH+k]*ob[k];
    (which ? Aenc : ua_enc)[s*CH + r] = acc;
  } else if (idx < 2*CS*CH + CH){
    int j = idx - 2*CS*CH;
    h_carry[j] = outf[(CS-1)*CH + j];
  }
}

// ---------------- fp32 -> bf16 (RNE) for lin_W ----------------
__global__ void k_cvt(const float* w, u16* o, int n){
  int i = blockIdx.x*blockDim.x + threadIdx.x;
  int stride = gridDim.x*blockDim.x;
  for (; i<n; i+=stride){
    union { float f; u32 u; } v; v.f = w[i];
    u32 r = (v.u + 0x7fffu + ((v.u>>16)&1u)) >> 16;
    o[i] = (u16)r;
  }
}

// ---------------- wah = wa @ h (pre-loop only) ----------------
__global__ void k_wah(const float* wa, const float* h, float* wah){
  int j = blockIdx.x*64 + (threadIdx.x>>2);
  int c0 = (threadIdx.x&3)*128;
  const float* w = wa + (long)j*CH;
  float acc = 0.f;
  #pragma unroll 4
  for (int k=c0;k<c0+128;k++) acc += w[k]*h[k];
  acc += __shfl_xor(acc,1); acc += __shfl_xor(acc,2);
  if ((threadIdx.x&3)==0) wah[j] = acc;
}

// ---------------- attention scores e[s] ----------------
__global__ void k_attn(int t, const float* vc, const float* va,
                       const float* ua_enc, const float* cov_vec, const float* wah, float* e){
  int s = blockIdx.x, tid = threadIdx.x;
  __shared__ float red[4];
  float sum = 0.f;
  #pragma unroll
  for (int jj=0;jj<2;jj++){
    int j = tid + jj*256;
    float acc = ua_enc[s*CH + j] + wah[j];
    if (t > 0){
      const float* v = vc + (long)j*CH;
      const float* cvs = cov_vec + s*CH;
      #pragma unroll 4
      for (int k=0;k<CH;k++) acc += v[k]*cvs[k];
    }
    sum += va[j]*tanhf(acc);
  }
  for (int m=1;m<64;m<<=1) sum += __shfl_xor(sum,m);
  if ((tid&63)==0) red[tid>>6] = sum;
  __syncthreads();
  if (tid==0) e[s] = red[0]+red[1]+red[2]+red[3];
}

// ---------------- softmax + context ----------------
__global__ void k_soft(const float* e, const float* outf, const float* outb, float* alpha, float* ctx){
  int tid = threadIdx.x; // 128
  __shared__ float al[CS];
  __shared__ float rmax[2], rsum[2];
  float v = (tid<CS) ? e[tid] : -1e30f;
  float m = v;
  for (int k=1;k<64;k<<=1) m = fmaxf(m, __shfl_xor(m,k));
  if ((tid&63)==0) rmax[tid>>6] = m;
  __syncthreads();
  float gm = fmaxf(rmax[0], rmax[1]);
  float ex = (tid<CS) ? expf(v-gm) : 0.f;
  float sm2 = ex;
  for (int k=1;k<64;k<<=1) sm2 += __shfl_xor(sm2,k);
  if ((tid&63)==0) rsum[tid>>6] = sm2;
  __syncthreads();
  float inv = 1.f/(rsum[0]+rsum[1]);
  if (tid<CS){ float a = ex*inv; al[tid] = a; alpha[tid] = a; }
  __syncthreads();
  #pragma unroll
  for (int k=0;k<8;k++){
    int d = k*128 + tid;
    const float* src = (d<CH) ? outf : outb;
    int dd = (d<CH) ? d : d-CH;
    float acc = 0.f;
    for (int s2=0;s2<CS;s2++) acc += al[s2]*src[s2*CH+dd];
    ctx[d] = acc;
  }
}

// ---------------- decoder GRU ----------------
__global__ void k_gru(int t, const float* Wi, const float* bi, const float* Wh, const float* bh,
                      const float* ctx, const float* x_dec, const float* h_carry, float* h_cur){
  int wg = blockIdx.x, tid = threadIdx.x;
  int j = wg*8 + (tid>>5);
  int ln = tid&31;
  const float* xd = x_dec + t*CE;
  float ar=0.f, az=0.f, an=0.f;
  {
    int c0 = ln*40;
    const float* wr = Wi + (long)j*CXD;
    const float* wz = Wi + (long)(j+CH)*CXD;
    const float* wn = Wi + (long)(j+2*CH)*CXD;
    for (int k=c0;k<c0+40;k++){
      float x = (k<CH2) ? ctx[k] : xd[k-CH2];
      ar += wr[k]*x; az += wz[k]*x; an += wn[k]*x;
    }
  }
  float hr=0.f, hz=0.f, hn2=0.f;
  {
    int c0 = ln*16;
    const float* wr = Wh + (long)j*CH;
    const float* wz = Wh + (long)(j+CH)*CH;
    const float* wn = Wh + (long)(j+2*CH)*CH;
    for (int k=c0;k<c0+16;k++){
      float hv = h_carry[k];
      hr += wr[k]*hv; hz += wz[k]*hv; hn2 += wn[k]*hv;
    }
  }
  for (int m=1;m<32;m<<=1){
    ar+=__shfl_xor(ar,m); az+=__shfl_xor(az,m); an+=__shfl_xor(an,m);
    hr+=__shfl_xor(hr,m); hz+=__shfl_xor(hz,m); hn2+=__shfl_xor(hn2,m);
  }
  if (ln==0){
    float hprev = h_carry[j];
    float r = sigm(ar + bi[j]       + hr + bh[j]);
    float z = sigm(az + bi[j+CH]    + hz + bh[j+CH]);
    float n = tanhf(an + bi[j+2*CH] + r*(hn2 + bh[j+2*CH]));
    h_cur[j] = (1.f-z)*n + z*hprev;
  }
}

// ---------------- fused tail, 64 blocks x 1024 ----------------
// cov ranks: bid in {0,8,16,24} (same XCD if bid%8 round-robin holds)
// wah: bid 1, 9.  logits: the other 58 blocks (928 row-walkers).
// Exchange: hxF (workgroup-scope swaps, local-L2 fast path, may be stale cross-XCD)
//           hxS (agent-scope tagged stores, MALL, always correct).  Tags make
//           staleness harmless; bounded fast trial falls back to hxS.
template<int BF16>
__launch_bounds__(1024)
__global__ void k_tail(int t, const void* Wv, const float* lb, const float* h_cur, const float* ctx,
                       float* out, const float* wa, float* wah,
                       const float* Whc, const float* Wic, const float* bic, const float* bhc,
                       const float* Aenc, const float* alpha,
                       float* cov_vec, float* cov_last, u64* hxF, u64* hxS, float* h_carry){
  int bid = blockIdx.x, tid = threadIdx.x;

  if (!(bid < 32 && (bid & 7) == 0)){
    if (bid == 1 || bid == 9){
      if (t > 0){
        int j = (bid==9)*256 + (tid>>2);
        int cq = (tid&3)*128;
        const float* w = wa + (long)j*CH;
        float acc = 0.f;
        #pragma unroll 4
        for (int k=cq;k<cq+128;k++) acc += w[k]*h_cur[k];
        acc += __shfl_xor(acc,1); acc += __shfl_xor(acc,2);
        if ((tid&3)==0) wah[j] = acc;
      }
      return;
    }
    // logits
    int li = bid - ((bid>0)+(bid>1)+(bid>8)+(bid>9)+(bid>16)+(bid>24));
    int ln = tid&63;
    int gw = li*16 + (tid>>6);     // 0..927
    float x[24];
    #pragma unroll
    for (int k=0;k<24;k++){
      int c = k*64 + ln;
      x[k] = (c<CH) ? h_cur[c] : ctx[c-CH];
    }
    for (int r=gw; r<CV; r+=928){
      float acc = 0.f;
      if (BF16){
        const u16* w = (const u16*)Wv + (long)r*CH3;
        #pragma unroll
        for (int k=0;k<24;k++){
          u32 u = (u32)w[k*64+ln] << 16;
          acc += __uint_as_float(u)*x[k];
        }
      } else {
        const float* w = (const float*)Wv + (long)r*CH3;
        #pragma unroll
        for (int k=0;k<24;k++) acc += w[k*64+ln]*x[k];
      }
      for (int m=1;m<64;m<<=1) acc += __shfl_xor(acc,m);
      if (ln==0) out[(long)t*CV + r] = acc + lb[r];
    }
    return;
  }

  // ================= coverage =================
  int wg = bid>>3;               // 0..3
  int part = tid>>7;             // 0..7  (wave pair)
  int lrow = tid&127;
  int grow = wg*128 + lrow;
  u32 vbase = (u32)(t*CS);
  const float* h_dec = (t==0) ? h_carry : h_cur;

  __shared__ float c_lds[CS][128];
  __shared__ float hv_lds[CS][128];
  __shared__ u32  h16[2][256];
  __shared__ float part_lds[8][128];
  __shared__ float al[CS];
  __shared__ int fast_fail;

  // fp16 weights -> regs: own row, own 64-k window
  u32 wreg[32];
  {
    const float* wp = Whc + (long)grow*CH + (part<<6);
    #pragma unroll
    for (int k=0;k<32;k++) wreg[k] = packh2(wp[2*k], wp[2*k+1]);
  }
  if (tid < CS) al[tid] = alpha[tid];
  if (tid == 0) fast_fail = 0;
  if (tid < 256) h16[0][tid] = 0u;

  // prologue (r4-style mapping): bacc, c_lds, cov_vec[0], carry commit
  {
    int prow = tid>>3, ppart = tid&7, pc0 = ppart*64;
    int growp = wg*128 + prow;
    float bacc = 0.f;
    const float* bp = Wic + (long)growp*CH3 + CH2 + pc0;
    #pragma unroll
    for (int k=0;k<64;k++) bacc += bp[k]*h_dec[pc0+k];
    for (int m=1;m<8;m<<=1) bacc += __shfl_xor(bacc,m);
    if (ppart==0){
      cov_vec[growp] = tanhf(cov_last[growp]);
      if (t > 0) h_carry[growp] = h_dec[growp];
    }
    __syncthreads();   // al ready
    float bsum = bic[growp] + bhc[growp];
    for (int s2=ppart*12; s2<ppart*12+12; s2++)
      c_lds[s2][prow] = al[s2]*(Aenc[s2*CH+growp] + bacc) + bsum;
  }
  __syncthreads();     // c_lds + h16[0] ready

  int cur = 0;
  for (int s=0;s<CS;s++){
    int nxt = cur^1;
    // dot: own 64-k fp16 window vs packed h (broadcast uint4 reads)
    {
      const uint4* hp = (const uint4*)&h16[cur][part<<5];
      float acc = 0.f;
      #pragma unroll
      for (int k=0;k<8;k++){
        uint4 hv = hp[k];
        acc = dot2f(wreg[4*k+0], hv.x, acc);
        acc = dot2f(wreg[4*k+1], hv.y, acc);
        acc = dot2f(wreg[4*k+2], hv.z, acc);
        acc = dot2f(wreg[4*k+3], hv.w, acc);
      }
      part_lds[part][lrow] = acc;
    }
    __syncthreads();   // B1: partials ready

    if (tid < 128){
      // wave pair 0: reduce + tanh + publish
      float tot = c_lds[s][tid];
      #pragma unroll
      for (int p=0;p<8;p++) tot += part_lds[p][tid];
      float hn = tanhf(tot);
      hv_lds[s][tid] = hn;
      if (s < CS-1){
        int slot = nxt*CH + wg*128 + tid;
        u64 pk = ((u64)(vbase + (u32)s + 1u) << 32) | (u64)__float_as_uint(hn);
        __hip_atomic_exchange(&hxF[slot], pk, __ATOMIC_RELAXED, __HIP_MEMORY_SCOPE_WORKGROUP);
        __hip_atomic_store(&hxS[slot], pk, __ATOMIC_RELAXED, __HIP_MEMORY_SCOPE_AGENT);
        float hn1 = __shfl_xor(hn, 1);
        if (!(tid&1)) h16[nxt][(wg<<6) + (tid>>1)] = packh2(hn, hn1);
      }
    } else if (s < CS-1 && tid < 320){
      // spinners (waves 2-4): 192 threads x 2 foreign rows
      int g = tid - 128;
      int q = g + ((g >= wg*64) ? 64 : 0);    // foreign pair index
      int r0 = q*2;
      u32 want = vbase + (u32)s + 1u;
      const u64* pF = &hxF[nxt*CH + r0];
      const u64* pS = &hxS[nxt*CH + r0];
      u64 a=0, b2=0; bool ok=false;
      if (!fast_fail){
        int fmax_it = (s<2) ? 4096 : 384;
        for (int it=0; it<fmax_it; ++it){
          a  = __hip_atomic_load(pF,   __ATOMIC_RELAXED, __HIP_MEMORY_SCOPE_WORKGROUP);
          b2 = __hip_atomic_load(pF+1, __ATOMIC_RELAXED, __HIP_MEMORY_SCOPE_WORKGROUP);
          if ((u32)(a>>32) >= want && (u32)(b2>>32) >= want){ ok = true; break; }
        }
        if (!ok) fast_fail = 1;
      }
      if (!ok){
        int gd = 0;
        do {
          a  = __hip_atomic_load(pS,   __ATOMIC_RELAXED, __HIP_MEMORY_SCOPE_AGENT);
          b2 = __hip_atomic_load(pS+1, __ATOMIC_RELAXED, __HIP_MEMORY_SCOPE_AGENT);
        } while (((u32)(a>>32) < want || (u32)(b2>>32) < want) && ++gd < 100000);
      }
      h16[nxt][q] = packh2(__uint_as_float((u32)a), __uint_as_float((u32)b2));
    }
    __syncthreads();   // B2: h16[nxt] ready
    cur = nxt;
  }

  // epilogue: tanh + cov_vec / cov_last stores (off serial path)
  for (int idx = tid; idx < CS*128; idx += 1024){
    int s2 = idx>>7, r = idx&127;
    if (s2 < CS-1) cov_vec[(s2+1)*CH + wg*128 + r] = tanhf(hv_lds[s2][r]);
  }
  if (tid < 128) cov_last[wg*128 + tid] = hv_lds[CS-1][tid];
}

// ---------------- host ----------------
extern "C" void kernel_launch(void* const* d_in, const int* in_sizes, int n_in,
                              void* d_out, int out_size, void* d_ws, size_t ws_size,
                              hipStream_t stream){
  (void)in_sizes; (void)n_in; (void)out_size;
  const int*   iseq = (const int*)d_in[0];
  const int*   oseq = (const int*)d_in[1];
  const float* ee   = (const float*)d_in[2];
  const float* de   = (const float*)d_in[3];
  const float* Wih_f=(const float*)d_in[4];  const float* Whh_f=(const float*)d_in[5];
  const float* bih_f=(const float*)d_in[6];  const float* bhh_f=(const float*)d_in[7];
  const float* Wih_b=(const float*)d_in[8];  const float* Whh_b=(const float*)d_in[9];
  const float* bih_b=(const float*)d_in[10]; const float* bhh_b=(const float*)d_in[11];
  const float* Wih_d=(const float*)d_in[12]; const float* Whh_d=(const float*)d_in[13];
  const float* bih_d=(const float*)d_in[14]; const float* bhh_d=(const float*)d_in[15];
  const float* Wih_c=(const float*)d_in[16]; const float* Whh_c=(const float*)d_in[17];
  const float* bih_c=(const float*)d_in[18]; const float* bhh_c=(const float*)d_in[19];
  const float* va   =(const float*)d_in[20]; const float* wa   =(const float*)d_in[21];
  const float* ua   =(const float*)d_in[22]; const float* vc   =(const float*)d_in[23];
  const float* lin_W=(const float*)d_in[24]; const float* lin_b=(const float*)d_in[25];
  float* out = (float*)d_out;
  char* ws = (char*)d_ws;

  size_t off = 0;
  auto A = [&](size_t bytes){ size_t r = off; off = (off + bytes + 255) & ~(size_t)255; return r; };
  size_t o_xenc = A((size_t)CS*CE*4), o_xdec = A((size_t)CT*CE*4);
  size_t o_gf   = A((size_t)CS*CH3*4), o_gb  = A((size_t)CS*CH3*4);
  size_t o_of   = A((size_t)CS*CH*4),  o_ob  = A((size_t)CS*CH*4);
  size_t o_uae  = A((size_t)CS*CH*4),  o_Ae  = A((size_t)CS*CH*4);
  size_t o_e    = A(CS*4), o_al = A(CS*4), o_ctx = A(CH2*4);
  size_t o_hc   = A(CH*4), o_hn = A(CH*4), o_cl = A(CH*4);
  size_t o_wah  = A(CH*4);
  size_t o_cv   = A((size_t)CS*CH*4);
  size_t o_hxF  = A(2*CH*8), o_hxS = A(2*CH*8);
  size_t o_lwb  = A((size_t)CV*CH3*2);
  bool use16 = (off <= ws_size);

  float* x_enc = (float*)(ws+o_xenc); float* x_dec = (float*)(ws+o_xdec);
  float* gf = (float*)(ws+o_gf);      float* gb = (float*)(ws+o_gb);
  float* outf = (float*)(ws+o_of);    float* outb = (float*)(ws+o_ob);
  float* ua_enc = (float*)(ws+o_uae); float* Aenc = (float*)(ws+o_Ae);
  float* e = (float*)(ws+o_e);        float* alpha = (float*)(ws+o_al);
  float* ctx = (float*)(ws+o_ctx);
  float* h_carry = (float*)(ws+o_hc); float* h_cur = (float*)(ws+o_hn);
  float* cov_last = (float*)(ws+o_cl);
  float* wah = (float*)(ws+o_wah);
  float* cov_vec = (float*)(ws+o_cv);
  u64* hxF = (u64*)(ws+o_hxF);        u64* hxS = (u64*)(ws+o_hxS);
  u16* lwb = (u16*)(ws+o_lwb);

  k_init<<<1,256,0,stream>>>((u32*)hxF, cov_last);   // hxF+hxS contiguous: 8*CH u32
  k_embed<<<CS,256,0,stream>>>(iseq, oseq, ee, de, x_enc, x_dec);
  k_gi<<<(2*CS*CH3)/256,256,0,stream>>>(Wih_f,bih_f,Wih_b,bih_b,x_enc,gf,gb);
  for (int s=0;s<CS;s++)
    k_enc_step<<<16,256,0,stream>>>(s, Whh_f,bhh_f,Whh_b,bhh_b, gf,gb, outf,outb);
  k_prep2<<<(2*CS*CH+CH)/256,256,0,stream>>>(ua, Wih_c, outf, outb, ua_enc, Aenc, h_carry);
  if (use16)
    k_cvt<<<2048,256,0,stream>>>(lin_W, lwb, CV*CH3);
  k_wah<<<8,256,0,stream>>>(wa, h_carry, wah);   // initial wah = wa @ h_enc

  for (int t=0;t<CT;t++){
    k_attn<<<CS,256,0,stream>>>(t, vc, va, ua_enc, cov_vec, wah, e);
    k_soft<<<1,128,0,stream>>>(e, outf, outb, alpha, ctx);
    k_gru<<<64,256,0,stream>>>(t, Wih_d,bih_d,Whh_d,bhh_d, ctx, x_dec, h_carry, h_cur);
    if (use16)
      k_tail<1><<<64,1024,0,stream>>>(t, (const void*)lwb, lin_b, h_cur, ctx, out, wa, wah,
                                      Whh_c, Wih_c, bih_c, bhh_c, Aenc, alpha,
                                      cov_vec, cov_last, hxF, hxS, h_carry);
    else
      k_tail<0><<<64,1024,0,stream>>>(t, (const void*)lin_W, lin_b, h_cur, ctx, out, wa, wah,
                                      Whh_c, Wih_c, bih_c, bhh_c, Aenc, alpha,
                                      cov_vec, cov_last, hxF, hxS, h_carry);
  }
}

// Round 6
// 38010.995 us; speedup vs baseline: 2.0720x; 2.0720x over previous
//
#include <hip/hip_runtime.h>
#include <hip/hip_bf16.h>
#include <hip/hip_fp16.h>
#include <math.h>

#define CS 96      // source len
#define CT 96      // target len
#define CE 256     // embed
#define CH 512     // hidden
#define CH2 1024
#define CH3 1536
#define CV 32000
#define CXD 1280   // E + 2H

typedef unsigned int u32;
typedef unsigned short u16;
typedef unsigned long long u64;

__device__ __forceinline__ float sigm(float x){ return 1.f/(1.f+expf(-x)); }

// packed-fp16 dot2 with fp32 accumulate
__device__ __forceinline__ float dot2f(u32 a, u32 b, float c){
#if __has_builtin(__builtin_amdgcn_fdot2)
  typedef _Float16 hv2 __attribute__((ext_vector_type(2)));
  hv2 x = __builtin_bit_cast(hv2, a), y = __builtin_bit_cast(hv2, b);
  return __builtin_amdgcn_fdot2(x, y, c, false);
#else
  __half2 x = __builtin_bit_cast(__half2, a), y = __builtin_bit_cast(__half2, b);
  return c + __half2float(x.x)*__half2float(y.x) + __half2float(x.y)*__half2float(y.y);
#endif
}

__device__ __forceinline__ u32 packh2(float a, float b){
  return (u32)__half_as_ushort(__float2half(a)) | ((u32)__half_as_ushort(__float2half(b)) << 16);
}

// ---------------- init: exchange slots + cov_last ----------------
__global__ void k_init(u32* hx, float* cov_last){
  int i = threadIdx.x;
  for (int j = i; j < 1024; j += 256) hx[j] = 0u;   // hc[2][256] u64 -> 1024 u32, tag=0
  for (int j = i; j < CH; j += 256) cov_last[j] = 0.f;
}

// ---------------- embedding gathers ----------------
__global__ void k_embed(const int* iseq, const int* oseq, const float* ee, const float* de,
                        float* x_enc, float* x_dec){
  int s = blockIdx.x, d = threadIdx.x;
  x_enc[s*CE+d] = ee[(long)iseq[s]*CE + d];
  x_dec[s*CE+d] = de[(long)oseq[s]*CE + d];
}

// ---------------- encoder input-gate precompute ----------------
__global__ void k_gi(const float* Wf, const float* bf, const float* Wb, const float* bb,
                     const float* x_enc, float* gf, float* gb){
  int idx = blockIdx.x*256 + threadIdx.x;
  int dir = idx / (CS*CH3);
  int rem = idx - dir*(CS*CH3);
  int s = rem / CH3, r = rem - s*CH3;
  const float* W = dir ? Wb : Wf;
  const float* b = dir ? bb : bf;
  const float* x = x_enc + s*CE;
  const float* w = W + (long)r*CE;
  float acc = b[r];
  #pragma unroll 8
  for (int k=0;k<CE;k++) acc += w[k]*x[k];
  (dir ? gb : gf)[s*CH3 + r] = acc;
}

// ---------------- one encoder step ----------------
__global__ void k_enc_step(int s, const float* Whf, const float* bhf, const float* Whb, const float* bhb,
                           const float* gf, const float* gb, float* outf, float* outb){
  int wg = blockIdx.x;
  int dir = wg >> 3;
  int jb = (wg & 7)*64;
  int t = threadIdx.x;
  int j = jb + (t>>2);
  int c0 = (t&3)*128;
  const float* Whh = dir ? Whb : Whf;
  const float* bhh = dir ? bhb : bhf;
  const float* gi  = dir ? gb : gf;
  float* o = dir ? outb : outf;
  int pos = dir ? (CS-1-s) : s;
  const float* hp = (s>0) ? (o + (dir ? (pos+1)*CH : (s-1)*CH)) : nullptr;
  float ar=0.f, az=0.f, an=0.f;
  if (s > 0){
    const float* wr = Whh + (long)j*CH;
    const float* wz = Whh + (long)(j+CH)*CH;
    const float* wn = Whh + (long)(j+2*CH)*CH;
    #pragma unroll 4
    for (int k=c0;k<c0+128;k++){
      float h = hp[k];
      ar += wr[k]*h; az += wz[k]*h; an += wn[k]*h;
    }
  }
  ar += __shfl_xor(ar,1); ar += __shfl_xor(ar,2);
  az += __shfl_xor(az,1); az += __shfl_xor(az,2);
  an += __shfl_xor(an,1); an += __shfl_xor(an,2);
  if ((t&3)==0){
    const float* g = gi + pos*CH3;
    float hpj = (s>0) ? hp[j] : 0.f;
    float r = sigm(g[j]       + ar + bhh[j]);
    float z = sigm(g[j+CH]    + az + bhh[j+CH]);
    float n = tanhf(g[j+2*CH] + r*(an + bhh[j+2*CH]));
    o[pos*CH + j] = (1.f-z)*n + z*hpj;
  }
}

// ---------------- ua_enc / Aenc precompute + h_carry init ----------------
__global__ void k_prep2(const float* ua, const float* Wic, const float* outf, const float* outb,
                        float* ua_enc, float* Aenc, float* h_carry){
  int idx = blockIdx.x*256 + threadIdx.x;
  if (idx < 2*CS*CH){
    int which = idx / (CS*CH);
    int rem = idx - which*(CS*CH);
    int s = rem / CH, r = rem - s*CH;
    const float* of = outf + s*CH;
    const float* ob = outb + s*CH;
    const float* w = which ? (Wic + (long)r*CH3) : (ua + (long)r*CH2);
    float acc = 0.f;
    #pragma unroll 4
    for (int k=0;k<CH;k++) acc += w[k]*of[k];
    #pragma unroll 4
    for (int k=0;k<CH;k++) acc += w[CH+k]*ob[k];
    (which ? Aenc : ua_enc)[s*CH + r] = acc;
  } else if (idx < 2*CS*CH + CH){
    int j = idx - 2*CS*CH;
    h_carry[j] = outf[(CS-1)*CH + j];
  }
}

// ---------------- fp32 -> bf16 (RNE) for lin_W ----------------
__global__ void k_cvt(const float* w, u16* o, int n){
  int i = blockIdx.x*blockDim.x + threadIdx.x;
  int stride = gridDim.x*blockDim.x;
  for (; i<n; i+=stride){
    union { float f; u32 u; } v; v.f = w[i];
    u32 r = (v.u + 0x7fffu + ((v.u>>16)&1u)) >> 16;
    o[i] = (u16)r;
  }
}

// ---------------- wah = wa @ h (pre-loop only) ----------------
__global__ void k_wah(const float* wa, const float* h, float* wah){
  int j = blockIdx.x*64 + (threadIdx.x>>2);
  int c0 = (threadIdx.x&3)*128;
  const float* w = wa + (long)j*CH;
  float acc = 0.f;
  #pragma unroll 4
  for (int k=c0;k<c0+128;k++) acc += w[k]*h[k];
  acc += __shfl_xor(acc,1); acc += __shfl_xor(acc,2);
  if ((threadIdx.x&3)==0) wah[j] = acc;
}

// ---------------- attention scores e[s] ----------------
__global__ void k_attn(int t, const float* vc, const float* va,
                       const float* ua_enc, const float* cov_vec, const float* wah, float* e){
  int s = blockIdx.x, tid = threadIdx.x;
  __shared__ float red[4];
  float sum = 0.f;
  #pragma unroll
  for (int jj=0;jj<2;jj++){
    int j = tid + jj*256;
    float acc = ua_enc[s*CH + j] + wah[j];
    if (t > 0){
      const float* v = vc + (long)j*CH;
      const float* cvs = cov_vec + s*CH;
      #pragma unroll 4
      for (int k=0;k<CH;k++) acc += v[k]*cvs[k];
    }
    sum += va[j]*tanhf(acc);
  }
  for (int m=1;m<64;m<<=1) sum += __shfl_xor(sum,m);
  if ((tid&63)==0) red[tid>>6] = sum;
  __syncthreads();
  if (tid==0) e[s] = red[0]+red[1]+red[2]+red[3];
}

// ---------------- softmax + context ----------------
__global__ void k_soft(const float* e, const float* outf, const float* outb, float* alpha, float* ctx){
  int tid = threadIdx.x; // 128
  __shared__ float al[CS];
  __shared__ float rmax[2], rsum[2];
  float v = (tid<CS) ? e[tid] : -1e30f;
  float m = v;
  for (int k=1;k<64;k<<=1) m = fmaxf(m, __shfl_xor(m,k));
  if ((tid&63)==0) rmax[tid>>6] = m;
  __syncthreads();
  float gm = fmaxf(rmax[0], rmax[1]);
  float ex = (tid<CS) ? expf(v-gm) : 0.f;
  float sm2 = ex;
  for (int k=1;k<64;k<<=1) sm2 += __shfl_xor(sm2,k);
  if ((tid&63)==0) rsum[tid>>6] = sm2;
  __syncthreads();
  float inv = 1.f/(rsum[0]+rsum[1]);
  if (tid<CS){ float a = ex*inv; al[tid] = a; alpha[tid] = a; }
  __syncthreads();
  #pragma unroll
  for (int k=0;k<8;k++){
    int d = k*128 + tid;
    const float* src = (d<CH) ? outf : outb;
    int dd = (d<CH) ? d : d-CH;
    float acc = 0.f;
    for (int s2=0;s2<CS;s2++) acc += al[s2]*src[s2*CH+dd];
    ctx[d] = acc;
  }
}

// ---------------- decoder GRU ----------------
__global__ void k_gru(int t, const float* Wi, const float* bi, const float* Wh, const float* bh,
                      const float* ctx, const float* x_dec, const float* h_carry, float* h_cur){
  int wg = blockIdx.x, tid = threadIdx.x;
  int j = wg*8 + (tid>>5);
  int ln = tid&31;
  const float* xd = x_dec + t*CE;
  float ar=0.f, az=0.f, an=0.f;
  {
    int c0 = ln*40;
    const float* wr = Wi + (long)j*CXD;
    const float* wz = Wi + (long)(j+CH)*CXD;
    const float* wn = Wi + (long)(j+2*CH)*CXD;
    for (int k=c0;k<c0+40;k++){
      float x = (k<CH2) ? ctx[k] : xd[k-CH2];
      ar += wr[k]*x; az += wz[k]*x; an += wn[k]*x;
    }
  }
  float hr=0.f, hz=0.f, hn2=0.f;
  {
    int c0 = ln*16;
    const float* wr = Wh + (long)j*CH;
    const float* wz = Wh + (long)(j+CH)*CH;
    const float* wn = Wh + (long)(j+2*CH)*CH;
    for (int k=c0;k<c0+16;k++){
      float hv = h_carry[k];
      hr += wr[k]*hv; hz += wz[k]*hv; hn2 += wn[k]*hv;
    }
  }
  for (int m=1;m<32;m<<=1){
    ar+=__shfl_xor(ar,m); az+=__shfl_xor(az,m); an+=__shfl_xor(an,m);
    hr+=__shfl_xor(hr,m); hz+=__shfl_xor(hz,m); hn2+=__shfl_xor(hn2,m);
  }
  if (ln==0){
    float hprev = h_carry[j];
    float r = sigm(ar + bi[j]       + hr + bh[j]);
    float z = sigm(az + bi[j+CH]    + hz + bh[j+CH]);
    float n = tanhf(an + bi[j+2*CH] + r*(hn2 + bh[j+2*CH]));
    h_cur[j] = (1.f-z)*n + z*hprev;
  }
}

// ---------------- fused tail: blocks 0..3 coverage | 4..5 wah | 6..55 logits ----------------
// coverage exchange: fence-free tagged u64 (tag32 | 2 x fp16), agent scope.
// Producer: wave 15 stores 64 words (from pk_lds).  Consumers: waves 2..4 poll,
// one word per lane, single shot into fp16 LDS.  Storer/poller waves disjoint so
// no wave's poll waits on its own store ACKs.  2-slot ping-pong, tags monotonic.
template<int BF16>
__launch_bounds__(1024)
__global__ void k_tail(int t, const void* Wv, const float* lb, const float* h_cur, const float* ctx,
                       float* out, const float* wa, float* wah,
                       const float* Whc, const float* Wic, const float* bic, const float* bhc,
                       const float* Aenc, const float* alpha,
                       float* cov_vec, float* cov_last, u64* hc, float* h_carry){
  int b = blockIdx.x, tid = threadIdx.x;

  if (b >= 6){
    // ---- logits: 50 blocks x 16 waves = 800 row-walkers ----
    int ln = tid&63;
    int gw = (b-6)*16 + (tid>>6);   // 0..799
    float x[24];
    #pragma unroll
    for (int k=0;k<24;k++){
      int c = k*64 + ln;
      x[k] = (c<CH) ? h_cur[c] : ctx[c-CH];
    }
    for (int r=gw; r<CV; r+=800){
      float acc = 0.f;
      if (BF16){
        const u16* w = (const u16*)Wv + (long)r*CH3;
        #pragma unroll
        for (int k=0;k<24;k++){
          u32 u = (u32)w[k*64+ln] << 16;
          acc += __uint_as_float(u)*x[k];
        }
      } else {
        const float* w = (const float*)Wv + (long)r*CH3;
        #pragma unroll
        for (int k=0;k<24;k++) acc += w[k*64+ln]*x[k];
      }
      for (int m=1;m<64;m<<=1) acc += __shfl_xor(acc,m);
      if (ln==0) out[(long)t*CV + r] = acc + lb[r];
    }
    return;
  }

  if (b >= 4){
    // ---- wah = wa @ h_cur for next step (skip at t=0: keeps wa@h_enc) ----
    if (t > 0){
      int j = (b-4)*256 + (tid>>2);
      int cq = (tid&3)*128;
      const float* w = wa + (long)j*CH;
      float acc = 0.f;
      #pragma unroll 4
      for (int k=cq;k<cq+128;k++) acc += w[k]*h_cur[k];
      acc += __shfl_xor(acc,1); acc += __shfl_xor(acc,2);
      if ((tid&3)==0) wah[j] = acc;
    }
    return;
  }

  // ================= coverage =================
  int wg = b;              // 0..3
  int lrow = tid>>3;       // 0..127
  int row = wg*128 + lrow;
  int part = tid&7;
  u32 vbase = (u32)(t*CS);
  const float* h_dec = (t==0) ? h_carry : h_cur;

  __shared__ float c_lds[CS][128];        // additive inputs
  __shared__ float hv_lds[CS][128];       // raw h outputs (epilogue tanh)
  __shared__ u32  h16[2][288];            // fp16 h, phys = g + ((g>>5)<<2) (stride 36)
  __shared__ u32  pk_lds[64];             // own slice packed, for wave 15
  __shared__ float al[CS];

  // fp16 weights -> regs: own row, own 64-k window
  u32 wreg[32];
  {
    const float* wp = Whc + (long)row*CH + part*64;
    #pragma unroll
    for (int k=0;k<32;k++) wreg[k] = packh2(wp[2*k], wp[2*k+1]);
  }
  if (tid < CS) al[tid] = alpha[tid];

  // prologue: bacc = Wih_c[:,1024:1536] @ h_dec (own row), carry commit
  float bacc = 0.f;
  {
    const float* bp = Wic + (long)row*CH3 + CH2 + part*64;
    #pragma unroll
    for (int k=0;k<64;k++) bacc += bp[k]*h_dec[part*64+k];
  }
  for (int m=1;m<8;m<<=1) bacc += __shfl_xor(bacc,m);
  float cov_old = 0.f;
  if (part==0){
    cov_old = cov_last[row];
    if (t > 0) h_carry[row] = h_dec[row];
  }
  __syncthreads();   // al ready
  {
    float bsum = bic[row] + bhc[row];
    for (int s2=part*12; s2<part*12+12; s2++)
      c_lds[s2][lrow] = al[s2]*(Aenc[s2*CH+row] + bacc) + bsum;
  }
  __syncthreads();   // c_lds ready

  int cur = 0;
  for (int s=0;s<CS;s++){
    int nxt = cur^1;
    float hn;
    if (s == 0){
      hn = tanhf(c_lds[0][lrow]);          // h_prev = 0; valid on all part lanes
    } else {
      const uint4* hp = (const uint4*)&h16[cur][part*36];
      float acc = 0.f;
      #pragma unroll
      for (int k=0;k<8;k++){
        uint4 hv = hp[k];
        acc = dot2f(wreg[4*k+0], hv.x, acc);
        acc = dot2f(wreg[4*k+1], hv.y, acc);
        acc = dot2f(wreg[4*k+2], hv.z, acc);
        acc = dot2f(wreg[4*k+3], hv.w, acc);
      }
      acc += __shfl_xor(acc,1); acc += __shfl_xor(acc,2); acc += __shfl_xor(acc,4);
      hn = tanhf(acc + c_lds[s][lrow]);    // full sum on all 8 part lanes
    }
    if (part==0) hv_lds[s][lrow] = hn;
    if (s < CS-1){
      float hp8 = __shfl_xor(hn, 8);       // partner row lrow^... (tid^8 -> lrow+1)
      if ((tid&15)==0){
        u32 pk = packh2(hn, hp8);
        int g = wg*64 + (lrow>>1);
        h16[nxt][g + ((g>>5)<<2)] = pk;    // own slice direct to LDS
        pk_lds[lrow>>1] = pk;
      }
    }
    __syncthreads();   // B1: pk_lds + own h16 ready; prior h16[cur] reads done
    if (s < CS-1){
      int wv = tid>>6, ln = tid&63;
      if (wv == 15){
        u64 x = ((u64)(vbase + (u32)s + 1u) << 32) | (u64)pk_lds[ln];
        __hip_atomic_store(&hc[nxt*256 + wg*64 + ln], x, __ATOMIC_RELAXED, __HIP_MEMORY_SCOPE_AGENT);
      } else if (wv >= 2 && wv <= 4){
        int f = wv - 2;
        int fw = f + (f >= wg);
        u32 want = vbase + (u32)s + 1u;
        const u64* p = &hc[nxt*256 + fw*64 + ln];
        u64 x; int gd = 0;
        do {
          x = __hip_atomic_load(p, __ATOMIC_RELAXED, __HIP_MEMORY_SCOPE_AGENT);
        } while ((u32)(x>>32) < want && ++gd < 30000);   // bounded: never hangs
        int g = fw*64 + ln;
        h16[nxt][g + ((g>>5)<<2)] = (u32)x;
      }
    }
    __syncthreads();   // B2: h16[nxt] complete
    cur = nxt;
  }

  // epilogue: tanh + cov_vec / cov_last stores (off serial path)
  for (int idx = tid; idx < CS*128; idx += 1024){
    int s2 = idx>>7, r = idx&127;
    if (s2 < CS-1) cov_vec[(s2+1)*CH + wg*128 + r] = tanhf(hv_lds[s2][r]);
  }
  if (part==0){
    cov_vec[row] = tanhf(cov_old);
    cov_last[row] = hv_lds[CS-1][lrow];
  }
}

// ---------------- host ----------------
extern "C" void kernel_launch(void* const* d_in, const int* in_sizes, int n_in,
                              void* d_out, int out_size, void* d_ws, size_t ws_size,
                              hipStream_t stream){
  (void)in_sizes; (void)n_in; (void)out_size;
  const int*   iseq = (const int*)d_in[0];
  const int*   oseq = (const int*)d_in[1];
  const float* ee   = (const float*)d_in[2];
  const float* de   = (const float*)d_in[3];
  const float* Wih_f=(const float*)d_in[4];  const float* Whh_f=(const float*)d_in[5];
  const float* bih_f=(const float*)d_in[6];  const float* bhh_f=(const float*)d_in[7];
  const float* Wih_b=(const float*)d_in[8];  const float* Whh_b=(const float*)d_in[9];
  const float* bih_b=(const float*)d_in[10]; const float* bhh_b=(const float*)d_in[11];
  const float* Wih_d=(const float*)d_in[12]; const float* Whh_d=(const float*)d_in[13];
  const float* bih_d=(const float*)d_in[14]; const float* bhh_d=(const float*)d_in[15];
  const float* Wih_c=(const float*)d_in[16]; const float* Whh_c=(const float*)d_in[17];
  const float* bih_c=(const float*)d_in[18]; const float* bhh_c=(const float*)d_in[19];
  const float* va   =(const float*)d_in[20]; const float* wa   =(const float*)d_in[21];
  const float* ua   =(const float*)d_in[22]; const float* vc   =(const float*)d_in[23];
  const float* lin_W=(const float*)d_in[24]; const float* lin_b=(const float*)d_in[25];
  float* out = (float*)d_out;
  char* ws = (char*)d_ws;

  size_t off = 0;
  auto A = [&](size_t bytes){ size_t r = off; off = (off + bytes + 255) & ~(size_t)255; return r; };
  size_t o_xenc = A((size_t)CS*CE*4), o_xdec = A((size_t)CT*CE*4);
  size_t o_gf   = A((size_t)CS*CH3*4), o_gb  = A((size_t)CS*CH3*4);
  size_t o_of   = A((size_t)CS*CH*4),  o_ob  = A((size_t)CS*CH*4);
  size_t o_uae  = A((size_t)CS*CH*4),  o_Ae  = A((size_t)CS*CH*4);
  size_t o_e    = A(CS*4), o_al = A(CS*4), o_ctx = A(CH2*4);
  size_t o_hc   = A(CH*4), o_hn = A(CH*4), o_cl = A(CH*4);
  size_t o_wah  = A(CH*4);
  size_t o_cv   = A((size_t)CS*CH*4);
  size_t o_hx   = A(2*256*8);
  size_t o_lwb  = A((size_t)CV*CH3*2);
  bool use16 = (off <= ws_size);

  float* x_enc = (float*)(ws+o_xenc); float* x_dec = (float*)(ws+o_xdec);
  float* gf = (float*)(ws+o_gf);      float* gb = (float*)(ws+o_gb);
  float* outf = (float*)(ws+o_of);    float* outb = (float*)(ws+o_ob);
  float* ua_enc = (float*)(ws+o_uae); float* Aenc = (float*)(ws+o_Ae);
  float* e = (float*)(ws+o_e);        float* alpha = (float*)(ws+o_al);
  float* ctx = (float*)(ws+o_ctx);
  float* h_carry = (float*)(ws+o_hc); float* h_cur = (float*)(ws+o_hn);
  float* cov_last = (float*)(ws+o_cl);
  float* wah = (float*)(ws+o_wah);
  float* cov_vec = (float*)(ws+o_cv);
  u64* hc = (u64*)(ws+o_hx);
  u16* lwb = (u16*)(ws+o_lwb);

  k_init<<<1,256,0,stream>>>((u32*)hc, cov_last);
  k_embed<<<CS,256,0,stream>>>(iseq, oseq, ee, de, x_enc, x_dec);
  k_gi<<<(2*CS*CH3)/256,256,0,stream>>>(Wih_f,bih_f,Wih_b,bih_b,x_enc,gf,gb);
  for (int s=0;s<CS;s++)
    k_enc_step<<<16,256,0,stream>>>(s, Whh_f,bhh_f,Whh_b,bhh_b, gf,gb, outf,outb);
  k_prep2<<<(2*CS*CH+CH)/256,256,0,stream>>>(ua, Wih_c, outf, outb, ua_enc, Aenc, h_carry);
  if (use16)
    k_cvt<<<2048,256,0,stream>>>(lin_W, lwb, CV*CH3);
  k_wah<<<8,256,0,stream>>>(wa, h_carry, wah);   // initial wah = wa @ h_enc

  for (int t=0;t<CT;t++){
    k_attn<<<CS,256,0,stream>>>(t, vc, va, ua_enc, cov_vec, wah, e);
    k_soft<<<1,128,0,stream>>>(e, outf, outb, alpha, ctx);
    k_gru<<<64,256,0,stream>>>(t, Wih_d,bih_d,Whh_d,bhh_d, ctx, x_dec, h_carry, h_cur);
    if (use16)
      k_tail<1><<<56,1024,0,stream>>>(t, (const void*)lwb, lin_b, h_cur, ctx, out, wa, wah,
                                      Whh_c, Wih_c, bih_c, bhh_c, Aenc, alpha,
                                      cov_vec, cov_last, hc, h_carry);
    else
      k_tail<0><<<56,1024,0,stream>>>(t, (const void*)lin_W, lin_b, h_cur, ctx, out, wa, wah,
                                      Whh_c, Wih_c, bih_c, bhh_c, Aenc, alpha,
                                      cov_vec, cov_last, hc, h_carry);
  }
}